// Round 7
// baseline (181.015 us; speedup 1.0000x reference)
//
#include <hip/hip_runtime.h>

// DEC Student-t soft assignment, ALPHA=1 -> q_ij = 1/(1+d2_ij), row-normalized.
// d2 = ||h||^2 + ||c||^2 - 2 h.c ; cross term via bf16 MFMA, h_sq/c_sq exact fp32.
//
// R6 -> R7: restructure. Block = FULL row panel 64x1024 (KP), so row
// normalization fuses into the epilogue: norm_k deleted (-262 MB HBM),
// rowsum atomics deleted. K-loop is BARRIER-FREE: B is wave-private
// (each wave's 128 centroid rows, 8 KB/tile, per-wave LDS double buffer,
// per-wave counted vmcnt); A (64x32) lives in registers via direct global
// loads (8-wave redundant reads are L1 hits). Waves self-pace (m114
// co-scheduling). vmcnt ledger: 12 loads/iter (8 B gload_lds + 4 A
// dwordx4), steady wait vmcnt(12) = drain tile t's 12, keep tile t+1's.
// T2 granule swizzle p^((p>>3)&7) kept for B (verified 0-conflict R2-R6).

typedef unsigned short u16;
typedef __attribute__((ext_vector_type(8))) short bf16x8;  // 8 bf16 = 4 VGPRs
typedef __attribute__((ext_vector_type(4))) float f32x4;

#define N_ROWS 32768
#define K_CENT 1000
#define KP     1024
#define DDIM   1024
#define BM     64
#define BK     32
#define NT     32     // K-tiles

__device__ __forceinline__ u16 f2bf(float x) {
  unsigned u = __float_as_uint(x);
  u += 0x7fffu + ((u >> 16) & 1u);   // round-to-nearest-even
  return (u16)(u >> 16);
}

__device__ __forceinline__ void gload_lds16(const u16* g, u16* s) {
  __builtin_amdgcn_global_load_lds((__attribute__((address_space(1))) void*)g,
                                   (__attribute__((address_space(3))) void*)s,
                                   16, 0, 0);
}

// ---------------- prep kernels ----------------

__global__ __launch_bounds__(256) void prep_h(const float* __restrict__ h,
                                              u16* __restrict__ hb,
                                              float* __restrict__ hsq) {
  const int row = blockIdx.x;
  const int t = threadIdx.x;
  const float4 v = reinterpret_cast<const float4*>(h + (size_t)row * DDIM)[t];
  ushort4 b;
  b.x = f2bf(v.x); b.y = f2bf(v.y); b.z = f2bf(v.z); b.w = f2bf(v.w);
  reinterpret_cast<ushort4*>(hb + (size_t)row * DDIM)[t] = b;
  float ss = v.x * v.x + v.y * v.y + v.z * v.z + v.w * v.w;
#pragma unroll
  for (int m = 1; m < 64; m <<= 1) ss += __shfl_xor(ss, m);
  __shared__ float sbuf[4];
  if ((t & 63) == 0) sbuf[t >> 6] = ss;
  __syncthreads();
  if (t == 0) hsq[row] = sbuf[0] + sbuf[1] + sbuf[2] + sbuf[3];
}

__global__ __launch_bounds__(256) void prep_c(const float* __restrict__ c,
                                              u16* __restrict__ cb,
                                              float* __restrict__ csq) {
  const int row = blockIdx.x;
  const int t = threadIdx.x;
  if (row < K_CENT) {
    const float4 v = reinterpret_cast<const float4*>(c + (size_t)row * DDIM)[t];
    ushort4 b;
    b.x = f2bf(v.x); b.y = f2bf(v.y); b.z = f2bf(v.z); b.w = f2bf(v.w);
    reinterpret_cast<ushort4*>(cb + (size_t)row * DDIM)[t] = b;
    float ss = v.x * v.x + v.y * v.y + v.z * v.z + v.w * v.w;
#pragma unroll
    for (int m = 1; m < 64; m <<= 1) ss += __shfl_xor(ss, m);
    __shared__ float sbuf[4];
    if ((t & 63) == 0) sbuf[t >> 6] = ss;
    __syncthreads();
    if (t == 0) csq[row] = sbuf[0] + sbuf[1] + sbuf[2] + sbuf[3];
  } else {
    ushort4 z; z.x = z.y = z.z = z.w = 0;
    reinterpret_cast<ushort4*>(cb + (size_t)row * DDIM)[t] = z;
    if (t == 0) csq[row] = 1e30f;  // pad rows: q ~ 1/(1+1e30) ~ 0
  }
}

// ---------------- fused GEMM + softassign + row-normalize ----------------
// B stripe per wave: 128 rows x 32 k = 512 granules of 16 B. Logical granule
// g = 4*row_loc + j, stored at p = g ^ ((p>>3)&7)-involution (0 conflicts,
// verified R2-R6). gload_lds writes linearly -> global source pre-permuted.

__device__ __forceinline__ void stageB_w(const u16* __restrict__ gB, u16* sB,
                                         int w, int l, int t) {
#pragma unroll
  for (int i = 0; i < 8; ++i) {
    const int p = i * 64 + l;              // granule written (within stripe slot)
    const int g = p ^ ((p >> 3) & 7);      // logical granule fetched
    gload_lds16(gB + (size_t)(w * 128 + (g >> 2)) * DDIM + t * BK + (g & 3) * 8,
                sB + ((i * 64) << 3));     // uniform base; HW adds l*16 B
  }
}

__device__ __forceinline__ void loadA(const u16* __restrict__ gA, bf16x8* fA,
                                      int l, int t) {
  const int r = l & 15;
  const int kc = t * BK + (l >> 4) * 8;
#pragma unroll
  for (int m = 0; m < 4; ++m)
    fA[m] = *(const bf16x8*)(gA + (size_t)(m * 16 + r) * DDIM + kc);
}

__global__ __launch_bounds__(512) void gemm_row(const u16* __restrict__ hb,
                                                const u16* __restrict__ cb,
                                                const float* __restrict__ hsq,
                                                const float* __restrict__ csq,
                                                float* __restrict__ out) {
  __shared__ u16 Bs[8][2][128 * BK];  // 8 waves x 2 slots x 8 KB = 128 KB

  const int brow = blockIdx.x;
  const int tid = threadIdx.x;
  const int w = tid >> 6;
  const int l = tid & 63;

  const u16* gA = hb + (size_t)brow * BM * DDIM;
  const u16* gB = cb;
  u16* myB0 = &Bs[w][0][0];
  u16* myB1 = &Bs[w][1][0];

  // fragment offsets (u16 elems, stripe-slot-relative); bOff[n+... ] = bOff[n]
  // pattern: row_loc += 16 -> g += 64 -> XOR bits (3-5) unchanged -> off += 512
  int bOff0;
  {
    const int g = ((l & 15) << 2) | (l >> 4);
    bOff0 = (g ^ ((g >> 3) & 7)) << 3;
  }

  f32x4 acc[4][8] = {};
  bf16x8 fA0[4], fA1[4];

  // prologue: tile 0 in flight (12 loads/wave)
  stageB_w(gB, myB0, w, l, 0);
  loadA(gA, fA0, l, 0);

#define MFMA_HALF(FA, SB, NB)                                                  \
  {                                                                            \
    bf16x8 fB[4];                                                              \
    _Pragma("unroll") for (int n = 0; n < 4; ++n)                              \
        fB[n] = *(const bf16x8*)((SB) + bOff0 + ((NB) * 4 + n) * 512);         \
    _Pragma("unroll") for (int m = 0; m < 4; ++m)                              \
      _Pragma("unroll") for (int n = 0; n < 4; ++n)                            \
        acc[m][(NB) * 4 + n] = __builtin_amdgcn_mfma_f32_16x16x32_bf16(        \
            (FA)[m], fB[n], acc[m][(NB) * 4 + n], 0, 0, 0);                    \
  }

  // Iter t (wave-local, NO barriers): issue tile-(t+1) loads, wait vmcnt(12)
  // (drains tile t's 12, keeps t+1's 12 in flight), ds_read fB + 32 MFMA.
#define ITER(T, FAc, FAn, MYBc, MYBn, ISSUE, VMSTR)                            \
  {                                                                            \
    if (ISSUE) { stageB_w(gB, MYBn, w, l, (T) + 1); loadA(gA, FAn, l, (T) + 1); } \
    asm volatile("s_waitcnt vmcnt(" VMSTR ")" ::: "memory");                   \
    __builtin_amdgcn_s_setprio(1);                                             \
    MFMA_HALF(FAc, MYBc, 0)                                                    \
    MFMA_HALF(FAc, MYBc, 1)                                                    \
    __builtin_amdgcn_s_setprio(0);                                             \
  }

#pragma unroll 1
  for (int t = 0; t < NT - 2; t += 2) {
    ITER(t,     fA0, fA1, myB0, myB1, true, "12")
    ITER(t + 1, fA1, fA0, myB1, myB0, true, "12")
  }
  ITER(NT - 2, fA0, fA1, myB0, myB1, true,  "12")
  ITER(NT - 1, fA1, fA0, myB1, myB0, false, "0")
#undef ITER
#undef MFMA_HALF

  // ---------------- fused epilogue: q + row-normalize ----------------
  __builtin_amdgcn_s_barrier();               // re-converge; reuse Bs as f32 LDS
  float* part = (float*)&Bs[0][0][0];         // [8][64] wave partial rowsums
  float* inv  = part + 512;                   // [64]

  const int lr = (l >> 4) << 2;
  const int lc = l & 15;

  float rsv[4][4];                            // [m][r] partial row sums
#pragma unroll
  for (int m = 0; m < 4; ++m) {
    float hs[4];
#pragma unroll
    for (int r = 0; r < 4; ++r) hs[r] = hsq[brow * BM + m * 16 + lr + r];
#pragma unroll
    for (int r = 0; r < 4; ++r) rsv[m][r] = 0.f;
#pragma unroll
    for (int n = 0; n < 8; ++n) {
      const float cs = csq[w * 128 + n * 16 + lc];
#pragma unroll
      for (int r = 0; r < 4; ++r) {
        float d2 = hs[r] + cs - 2.0f * acc[m][n][r];
        d2 = fmaxf(d2, 0.0f);
        const float qv = 1.0f / (1.0f + d2);
        acc[m][n][r] = qv;
        rsv[m][r] += qv;
      }
    }
  }
  // reduce over the 16 column-lanes; lanes lc==0 hold sums for rows lr..lr+3
#pragma unroll
  for (int m = 0; m < 4; ++m)
#pragma unroll
    for (int r = 0; r < 4; ++r) {
      float v = rsv[m][r];
      v += __shfl_xor(v, 1);
      v += __shfl_xor(v, 2);
      v += __shfl_xor(v, 4);
      v += __shfl_xor(v, 8);
      if (lc == 0) part[w * 64 + m * 16 + lr + r] = v;
    }
  __syncthreads();
  if (tid < 64) {
    float s = 0.f;
#pragma unroll
    for (int w2 = 0; w2 < 8; ++w2) s += part[w2 * 64 + tid];
    inv[tid] = 1.0f / s;
  }
  __syncthreads();

  float iv[4][4];
#pragma unroll
  for (int m = 0; m < 4; ++m)
#pragma unroll
    for (int r = 0; r < 4; ++r) iv[m][r] = inv[m * 16 + lr + r];

#pragma unroll
  for (int m = 0; m < 4; ++m)
#pragma unroll
    for (int n = 0; n < 8; ++n) {
      const int col = w * 128 + n * 16 + lc;
      if (col < K_CENT) {
#pragma unroll
        for (int r = 0; r < 4; ++r)
          out[(size_t)(brow * BM + m * 16 + lr + r) * K_CENT + col] =
              acc[m][n][r] * iv[m][r];
      }
    }
}

// ---------------- launch ----------------

extern "C" void kernel_launch(void* const* d_in, const int* in_sizes, int n_in,
                              void* d_out, int out_size, void* d_ws, size_t ws_size,
                              hipStream_t stream) {
  const float* h   = (const float*)d_in[0];
  const float* cen = (const float*)d_in[1];
  float* out = (float*)d_out;
  char* ws = (char*)d_ws;

  u16*   cb  = (u16*)(ws);                          // 2 MB
  u16*   hb  = (u16*)(ws + 2097152);                // 64 MB
  float* hsq = (float*)(ws + 2097152 + 67108864);   // 128 KB
  float* csq = (float*)(ws + 2097152 + 67108864 + 131072);  // 4 KB

  prep_c<<<KP, 256, 0, stream>>>(cen, cb, csq);
  prep_h<<<N_ROWS, 256, 0, stream>>>(h, hb, hsq);
  gemm_row<<<N_ROWS / BM, 512, 0, stream>>>(hb, cb, hsq, csq, out);
}